// Round 3
// baseline (526.702 us; speedup 1.0000x reference)
//
#include <hip/hip_runtime.h>

// PSEAD attention. Math: scores_p = P_p (s*QK^T) P_p^T ;
// out_bh = (sum_p softmax(scores_p) P_p) V
// Dtype-adaptive: detects fp32 vs bf16 inputs at runtime (flag in ws),
// canonicalizes everything to bf16, runs MFMA pipeline, stores out per flag.

typedef unsigned short u16;
typedef unsigned int u32;
typedef __attribute__((ext_vector_type(8))) __bf16 bf16x8;
typedef __attribute__((ext_vector_type(4))) float f32x4;
typedef __attribute__((ext_vector_type(4))) u32 u32x4;
typedef __attribute__((address_space(1))) void gvoid;
typedef __attribute__((address_space(3))) void svoid;

#define MFMA16(a, b, c) __builtin_amdgcn_mfma_f32_16x16x32_bf16(a, b, c, 0, 0, 0)

__device__ __forceinline__ u16 f2bf(float f) {
  u32 u = __builtin_bit_cast(u32, f);
  return (u16)((u + 0x7fffu + ((u >> 16) & 1u)) >> 16);
}
__device__ __forceinline__ float bf2f(u16 h) {
  u32 u = ((u32)h) << 16;
  return __builtin_bit_cast(float, u);
}
__device__ __forceinline__ bf16x8 ld_frag(const u16* p) {
  u32x4 v = *reinterpret_cast<const u32x4*>(p);
  return __builtin_bit_cast(bf16x8, v);
}
// K=16 padded to K=32: lanes >= 32 supply zeros
__device__ __forceinline__ bf16x8 ld_frag_lo(const u16* p, int lane) {
  u32x4 v = {0u, 0u, 0u, 0u};
  if (lane < 32) v = *reinterpret_cast<const u32x4*>(p);
  return __builtin_bit_cast(bf16x8, v);
}
__device__ __forceinline__ void async16(const u16* g, u16* l) {
  __builtin_amdgcn_global_load_lds((gvoid*)g, (svoid*)l, 16, 0, 0);
}
// Per-wave LDS write->read fence: compiler memory barrier + DS-queue drain.
__device__ __forceinline__ void lds_fence() {
  asm volatile("s_waitcnt lgkmcnt(0)" ::: "memory");
}

// --------- dtype detection: fp32 exponents cluster in [64,191] --------------
__global__ __launch_bounds__(256) void detect_dtype(const u32* __restrict__ x,
                                                    int* __restrict__ flag) {
  const int tid = threadIdx.x;
  int cnt = 0;
  for (int i = tid; i < 16384; i += 256) {
    const u32 e = (x[i] >> 23) & 0xffu;
    cnt += (e >= 64u && e <= 191u) ? 1 : 0;
  }
  __shared__ int sred[4];
  for (int o = 32; o; o >>= 1) cnt += __shfl_down(cnt, o);
  if ((tid & 63) == 0) sred[tid >> 6] = cnt;
  __syncthreads();
  if (tid == 0)
    flag[0] = (sred[0] + sred[1] + sred[2] + sred[3] > 8192) ? 1 : 0;  // 1 = fp32
}

// --------- canonicalize: any src -> bf16 dst --------------------------------
__global__ __launch_bounds__(256) void convert_bf16(const void* __restrict__ src,
                                                    u16* __restrict__ dst, int n,
                                                    const int* __restrict__ flag) {
  const int isf32 = *flag;
  const int base = (blockIdx.x * 256 + threadIdx.x) * 8;
  if (base >= n) return;
  if (isf32) {
    const float* s = (const float*)src;
#pragma unroll
    for (int j = 0; j < 8; ++j) dst[base + j] = f2bf(s[base + j]);
  } else {
    const u16* s = (const u16*)src;
#pragma unroll
    for (int j = 0; j < 8; ++j) dst[base + j] = s[base + j];
  }
}

// --------- weight transpose+convert: dst[n][k] = bf16(src[k][n]), 1024x1024 -
__global__ __launch_bounds__(256) void transpose_conv(const void* __restrict__ src,
                                                      u16* __restrict__ dst,
                                                      const int* __restrict__ flag) {
  __shared__ u16 tile[32][33];
  const int isf32 = *flag;
  const int tx = threadIdx.x & 31;
  const int ty = (threadIdx.x >> 5) * 4;
  const int bx = blockIdx.x * 32;  // src col
  const int by = blockIdx.y * 32;  // src row
#pragma unroll
  for (int r = 0; r < 4; ++r) {
    const int idx = (by + ty + r) * 1024 + bx + tx;
    tile[ty + r][tx] = isf32 ? f2bf(((const float*)src)[idx]) : ((const u16*)src)[idx];
  }
  __syncthreads();
#pragma unroll
  for (int r = 0; r < 4; ++r)
    dst[(bx + ty + r) * 1024 + by + tx] = tile[tx][ty + r];
}

// ---------------- 128x128x(BK=32) bf16 MFMA GEMM, m97-style ------------------
// MODE 0: X[16384x1024] @ WtQKV^T -> scatter Q[bh][j][64], K[bh][j][64], Vt[bh][64][16]
// MODE 1: T[16384x1024] @ WtO^T + bo -> out[16384][1024] (fp32 or bf16 per flag)
template <int MODE>
__global__ __launch_bounds__(256) void gemm_kernel(
    const u16* __restrict__ X, const u16* __restrict__ Wt,
    const u16* __restrict__ b0, const u16* __restrict__ b1, const u16* __restrict__ b2,
    void* __restrict__ o0, u16* __restrict__ o1, u16* __restrict__ o2,
    const int* __restrict__ flag) {
  __shared__ alignas(16) u16 As[128 * 32];
  __shared__ alignas(16) u16 Bs[128 * 32];
  const int tid = threadIdx.x;
  const int wave = tid >> 6, lane = tid & 63;
  const int m0 = blockIdx.y * 128, n0 = blockIdx.x * 128;
  const int wm = (wave >> 1) * 64, wn = (wave & 1) * 64;
  const int fr = lane & 15, fq = lane >> 4;

  f32x4 acc[4][4] = {};

  const int s0 = tid, s1 = 256 + tid;
  const u16* gA0 = X + (m0 + (s0 >> 2)) * 1024 + (s0 & 3) * 8;
  const u16* gA1 = X + (m0 + (s1 >> 2)) * 1024 + (s1 & 3) * 8;
  const u16* gB0 = Wt + (n0 + (s0 >> 2)) * 1024 + (s0 & 3) * 8;
  const u16* gB1 = Wt + (n0 + (s1 >> 2)) * 1024 + (s1 & 3) * 8;
  u16* lA0 = As + wave * 64 * 8;
  u16* lA1 = As + (256 + wave * 64) * 8;
  u16* lB0 = Bs + wave * 64 * 8;
  u16* lB1 = Bs + (256 + wave * 64) * 8;
  const u16* aRd = As + (wm + fr) * 32 + fq * 8;
  const u16* bRd = Bs + (wn + fr) * 32 + fq * 8;

  for (int kb = 0; kb < 32; ++kb) {
    const int ko = kb * 32;
    if (kb) __syncthreads();
    async16(gA0 + ko, lA0);
    async16(gA1 + ko, lA1);
    async16(gB0 + ko, lB0);
    async16(gB1 + ko, lB1);
    __syncthreads();  // compiler emits s_waitcnt vmcnt(0) before s_barrier
    bf16x8 af[4], bfr[4];
#pragma unroll
    for (int t = 0; t < 4; ++t) af[t] = ld_frag(aRd + t * 16 * 32);
#pragma unroll
    for (int t = 0; t < 4; ++t) bfr[t] = ld_frag(bRd + t * 16 * 32);
#pragma unroll
    for (int i = 0; i < 4; ++i)
#pragma unroll
      for (int j = 0; j < 4; ++j) acc[i][j] = MFMA16(af[i], bfr[j], acc[i][j]);
  }

  const int c = fr, g = fq;
  if (MODE == 0) {
    const int q = n0 >> 10;  // 0=Q,1=K,2=V
    const int nb = (n0 & 1023) + wn;
    const u16* bp = (q == 0) ? b0 : ((q == 1) ? b1 : b2);
    u16* q0 = (u16*)o0;
#pragma unroll
    for (int tm = 0; tm < 4; ++tm) {
      const int mbase = m0 + wm + tm * 16;
      const int bidx = mbase >> 4;
#pragma unroll
      for (int tn = 0; tn < 4; ++tn) {
        const int nl = nb + tn * 16 + c;
        const int h = nl >> 6, d = nl & 63;
        const float bias = bf2f(bp[nl]);
        const int bh = bidx * 16 + h;
#pragma unroll
        for (int r = 0; r < 4; ++r) {
          const int j = g * 4 + r;
          const u16 hv = f2bf(acc[tm][tn][r] + bias);
          if (q == 0)
            q0[(bh * 16 + j) * 64 + d] = hv;           // Q[bh][j][d]
          else if (q == 1)
            o1[(bh * 16 + j) * 64 + d] = hv;           // K[bh][j][d]
          else
            o2[(bh * 64 + d) * 16 + j] = hv;           // Vt[bh][d][j]
        }
      }
    }
  } else {
    const int isf32 = *flag;
#pragma unroll
    for (int tm = 0; tm < 4; ++tm) {
      const int m = m0 + wm + tm * 16 + g * 4;
#pragma unroll
      for (int tn = 0; tn < 4; ++tn) {
        const int n = n0 + wn + tn * 16 + c;
        const float bias = bf2f(b0[n]);
        if (isf32) {
#pragma unroll
          for (int r = 0; r < 4; ++r)
            ((float*)o0)[(m + r) * 1024 + n] = acc[tm][tn][r] + bias;
        } else {
#pragma unroll
          for (int r = 0; r < 4; ++r)
            ((u16*)o0)[(m + r) * 1024 + n] = f2bf(acc[tm][tn][r] + bias);
        }
      }
    }
  }
}

// ---------------- attention: one wave per (b,h) ------------------------------
__global__ __launch_bounds__(256) void attn_kernel(
    const u16* __restrict__ Qb, const u16* __restrict__ Kb, const u16* __restrict__ Vt,
    const u16* __restrict__ P, u16* __restrict__ Tb) {
  __shared__ alignas(16) u16 Pl[4096];   // P[p][i][j]
  __shared__ alignas(16) u16 Ptl[4096];  // P^T
  __shared__ alignas(16) u16 STl[4][16 * 24];
  __shared__ alignas(16) u16 CVl[4][16 * 24];

  const int tid = threadIdx.x;
#pragma unroll
  for (int i = 0; i < 16; ++i) {
    const int idx = i * 256 + tid;
    const u16 v = P[idx];
    Pl[idx] = v;
    const int p = idx >> 8, rc = idx & 255, rr = rc >> 4, cc = rc & 15;
    Ptl[(p << 8) + (cc << 4) + rr] = v;
  }
  __syncthreads();

  const int wave = tid >> 6, lane = tid & 63;
  const int bh = blockIdx.x * 4 + wave;
  const int fr = lane & 15, fq = lane >> 4;
  const int c = fr, g = fq;
  u16* ST = STl[wave];
  u16* CV = CVl[wave];

  const u16* qb = Qb + bh * 1024;
  const u16* kb = Kb + bh * 1024;
  const u16* vb = Vt + bh * 1024;

  const bf16x8 qf0 = ld_frag(qb + fr * 64 + fq * 8);
  const bf16x8 qf1 = ld_frag(qb + fr * 64 + 32 + fq * 8);
  const bf16x8 kf0 = ld_frag(kb + fr * 64 + fq * 8);
  const bf16x8 kf1 = ld_frag(kb + fr * 64 + 32 + fq * 8);
  f32x4 S = {0.f, 0.f, 0.f, 0.f};
  S = MFMA16(qf0, kf0, S);
  S = MFMA16(qf1, kf1, S);
  const float scale = 0.125f;  // 1/sqrt(64)

#pragma unroll
  for (int r = 0; r < 4; ++r) ST[c * 24 + g * 4 + r] = f2bf(S[r] * scale);
  lds_fence();
  const bf16x8 sf = ld_frag_lo(ST + fr * 24 + fq * 8, lane);

  f32x4 Macc = {0.f, 0.f, 0.f, 0.f};
  for (int p = 0; p < 16; ++p) {
    const bf16x8 pa = ld_frag_lo(Pl + (p << 8) + fr * 16 + fq * 8, lane);
    f32x4 Ap = {0.f, 0.f, 0.f, 0.f};
    Ap = MFMA16(pa, sf, Ap);
#pragma unroll
    for (int r = 0; r < 4; ++r) CV[(g * 4 + r) * 24 + c] = f2bf(Ap[r]);
    lds_fence();
    const bf16x8 aa = ld_frag_lo(CV + fr * 24 + fq * 8, lane);
    f32x4 Bp = {0.f, 0.f, 0.f, 0.f};
    Bp = MFMA16(aa, pa, Bp);
    float w[4];
#pragma unroll
    for (int r = 0; r < 4; ++r) {
      const float v = Bp[r];
      float mx = v;
      mx = fmaxf(mx, __shfl_xor(mx, 1));
      mx = fmaxf(mx, __shfl_xor(mx, 2));
      mx = fmaxf(mx, __shfl_xor(mx, 4));
      mx = fmaxf(mx, __shfl_xor(mx, 8));
      const float e = __expf(v - mx);
      float sm = e;
      sm += __shfl_xor(sm, 1);
      sm += __shfl_xor(sm, 2);
      sm += __shfl_xor(sm, 4);
      sm += __shfl_xor(sm, 8);
      w[r] = e / sm;
    }
    lds_fence();
#pragma unroll
    for (int r = 0; r < 4; ++r) CV[(g * 4 + r) * 24 + c] = f2bf(w[r]);
    lds_fence();
    const bf16x8 wa = ld_frag_lo(CV + fr * 24 + fq * 8, lane);
    const bf16x8 pb = ld_frag_lo(Ptl + (p << 8) + fr * 16 + fq * 8, lane);
    Macc = MFMA16(wa, pb, Macc);
  }

  lds_fence();
#pragma unroll
  for (int r = 0; r < 4; ++r) CV[(g * 4 + r) * 24 + c] = f2bf(Macc[r]);
  lds_fence();
  const bf16x8 ma = ld_frag_lo(CV + fr * 24 + fq * 8, lane);

  const int b = bh >> 4, h = bh & 15;
  u16* outp = Tb + (b * 16) * 1024 + h * 64;
#pragma unroll
  for (int dt = 0; dt < 4; ++dt) {
    const bf16x8 vf = ld_frag_lo(vb + (dt * 16 + fr) * 16 + fq * 8, lane);
    f32x4 o = {0.f, 0.f, 0.f, 0.f};
    o = MFMA16(ma, vf, o);
#pragma unroll
    for (int r = 0; r < 4; ++r)
      outp[(g * 4 + r) * 1024 + dt * 16 + c] = f2bf(o[r]);
  }
}

// ---------------- launcher ---------------------------------------------------
extern "C" void kernel_launch(void* const* d_in, const int* in_sizes, int n_in,
                              void* d_out, int out_size, void* d_ws, size_t ws_size,
                              hipStream_t stream) {
  const void* x = d_in[0];
  const void* proj = d_in[1];
  const void* Wq = d_in[2];
  const void* bq = d_in[3];
  const void* Wk = d_in[4];
  const void* bk = d_in[5];
  const void* Wv = d_in[6];
  const void* bv = d_in[7];
  const void* Wo = d_in[8];
  const void* bo = d_in[9];

  char* ws = (char*)d_ws;
  int* flag = (int*)ws;          ws += 256;
  u16* bqc  = (u16*)ws;          ws += 1024 * 2;
  u16* bkc  = (u16*)ws;          ws += 1024 * 2;
  u16* bvc  = (u16*)ws;          ws += 1024 * 2;
  u16* boc  = (u16*)ws;          ws += 1024 * 2;
  u16* pjc  = (u16*)ws;          ws += 4096 * 2;
  u16* WtQKV = (u16*)ws;         ws += (size_t)3072 * 1024 * 2;
  u16* WtO   = (u16*)ws;         ws += (size_t)1024 * 1024 * 2;
  u16* Xb    = (u16*)ws;         ws += (size_t)16384 * 1024 * 2;
  u16* Qbuf  = (u16*)ws;         ws += (size_t)16384 * 1024 * 2;
  u16* Kbuf  = (u16*)ws;         ws += (size_t)16384 * 1024 * 2;
  u16* Vtb   = (u16*)ws;         ws += (size_t)16384 * 1024 * 2;
  u16* Tbuf  = (u16*)ws;         ws += (size_t)16384 * 1024 * 2;

  detect_dtype<<<1, 256, 0, stream>>>((const u32*)x, flag);

  convert_bf16<<<8192, 256, 0, stream>>>(x, Xb, 16777216, flag);
  convert_bf16<<<1, 256, 0, stream>>>(bq, bqc, 1024, flag);
  convert_bf16<<<1, 256, 0, stream>>>(bk, bkc, 1024, flag);
  convert_bf16<<<1, 256, 0, stream>>>(bv, bvc, 1024, flag);
  convert_bf16<<<1, 256, 0, stream>>>(bo, boc, 1024, flag);
  convert_bf16<<<2, 256, 0, stream>>>(proj, pjc, 4096, flag);

  const dim3 tg(32, 32);
  transpose_conv<<<tg, 256, 0, stream>>>(Wq, WtQKV, flag);
  transpose_conv<<<tg, 256, 0, stream>>>(Wk, WtQKV + 1024 * 1024, flag);
  transpose_conv<<<tg, 256, 0, stream>>>(Wv, WtQKV + 2 * 1024 * 1024, flag);
  transpose_conv<<<tg, 256, 0, stream>>>(Wo, WtO, flag);

  gemm_kernel<0><<<dim3(24, 128), 256, 0, stream>>>(Xb, WtQKV, bqc, bkc, bvc,
                                                    Qbuf, Kbuf, Vtb, nullptr);
  attn_kernel<<<4096, 256, 0, stream>>>(Qbuf, Kbuf, Vtb, pjc, Tbuf);
  gemm_kernel<1><<<dim3(8, 128), 256, 0, stream>>>(Tbuf, WtO, boc, nullptr, nullptr,
                                                   d_out, nullptr, nullptr, flag);
}

// Round 4
// 438.516 us; speedup vs baseline: 1.2011x; 1.2011x over previous
//
#include <hip/hip_runtime.h>

// PSEAD attention. Math: scores_p = P_p (s*QK^T) P_p^T ;
// out_bh = (sum_p softmax(scores_p) P_p) V
// Dtype-adaptive: detects fp32 vs bf16 inputs at runtime (flag in ws),
// canonicalizes everything to bf16, runs MFMA pipeline, stores out per flag.

typedef unsigned short u16;
typedef unsigned int u32;
typedef __attribute__((ext_vector_type(8))) __bf16 bf16x8;
typedef __attribute__((ext_vector_type(4))) float f32x4;
typedef __attribute__((ext_vector_type(4))) u32 u32x4;
typedef __attribute__((ext_vector_type(4))) u16 u16x4;
typedef __attribute__((address_space(1))) void gvoid;
typedef __attribute__((address_space(3))) void svoid;

#define MFMA16(a, b, c) __builtin_amdgcn_mfma_f32_16x16x32_bf16(a, b, c, 0, 0, 0)

__device__ __forceinline__ u16 f2bf(float f) {
  u32 u = __builtin_bit_cast(u32, f);
  return (u16)((u + 0x7fffu + ((u >> 16) & 1u)) >> 16);
}
__device__ __forceinline__ float bf2f(u16 h) {
  u32 u = ((u32)h) << 16;
  return __builtin_bit_cast(float, u);
}
__device__ __forceinline__ bf16x8 ld_frag(const u16* p) {
  u32x4 v = *reinterpret_cast<const u32x4*>(p);
  return __builtin_bit_cast(bf16x8, v);
}
// K=16 padded to K=32: lanes >= 32 supply zeros
__device__ __forceinline__ bf16x8 ld_frag_lo(const u16* p, int lane) {
  u32x4 v = {0u, 0u, 0u, 0u};
  if (lane < 32) v = *reinterpret_cast<const u32x4*>(p);
  return __builtin_bit_cast(bf16x8, v);
}
__device__ __forceinline__ void async16(const u16* g, u16* l) {
  __builtin_amdgcn_global_load_lds((gvoid*)g, (svoid*)l, 16, 0, 0);
}
// Per-wave LDS write->read fence: compiler memory barrier + DS-queue drain.
__device__ __forceinline__ void lds_fence() {
  asm volatile("s_waitcnt lgkmcnt(0)" ::: "memory");
}

// --------- dtype detection: fp32 exponents cluster in [64,191] --------------
__global__ __launch_bounds__(256) void detect_dtype(const u32* __restrict__ x,
                                                    int* __restrict__ flag) {
  const int tid = threadIdx.x;
  int cnt = 0;
  for (int i = tid; i < 16384; i += 256) {
    const u32 e = (x[i] >> 23) & 0xffu;
    cnt += (e >= 64u && e <= 191u) ? 1 : 0;
  }
  __shared__ int sred[4];
  for (int o = 32; o; o >>= 1) cnt += __shfl_down(cnt, o);
  if ((tid & 63) == 0) sred[tid >> 6] = cnt;
  __syncthreads();
  if (tid == 0)
    flag[0] = (sred[0] + sred[1] + sred[2] + sred[3] > 8192) ? 1 : 0;  // 1 = fp32
}

// --------- canonicalize: any src -> bf16 dst --------------------------------
__global__ __launch_bounds__(256) void convert_bf16(const void* __restrict__ src,
                                                    u16* __restrict__ dst, int n,
                                                    const int* __restrict__ flag) {
  const int isf32 = *flag;
  const int base = (blockIdx.x * 256 + threadIdx.x) * 8;
  if (base >= n) return;
  if (isf32) {
    const float* s = (const float*)src;
#pragma unroll
    for (int j = 0; j < 8; ++j) dst[base + j] = f2bf(s[base + j]);
  } else {
    const u16* s = (const u16*)src;
#pragma unroll
    for (int j = 0; j < 8; ++j) dst[base + j] = s[base + j];
  }
}

// --------- weight transpose+convert: dst[n][k] = bf16(src[k][n]), 1024x1024 -
__global__ __launch_bounds__(256) void transpose_conv(const void* __restrict__ src,
                                                      u16* __restrict__ dst,
                                                      const int* __restrict__ flag) {
  __shared__ u16 tile[32][33];
  const int isf32 = *flag;
  const int tx = threadIdx.x & 31;
  const int ty = (threadIdx.x >> 5) * 4;
  const int bx = blockIdx.x * 32;  // src col
  const int by = blockIdx.y * 32;  // src row
#pragma unroll
  for (int r = 0; r < 4; ++r) {
    const int idx = (by + ty + r) * 1024 + bx + tx;
    tile[ty + r][tx] = isf32 ? f2bf(((const float*)src)[idx]) : ((const u16*)src)[idx];
  }
  __syncthreads();
#pragma unroll
  for (int r = 0; r < 4; ++r)
    dst[(bx + ty + r) * 1024 + by + tx] = tile[tx][ty + r];
}

// ---------------- 128x128x(BK=32) bf16 MFMA GEMM, m97-style ------------------
// MODE 0: X[16384x1024] @ WtQKV^T -> scatter Q[bh][j][64], K[bh][j][64], Vt[bh][64][16]
// MODE 1: T[16384x1024] @ WtO^T + bo -> out[16384][1024] (fp32 or bf16 per flag)
template <int MODE>
__global__ __launch_bounds__(256) void gemm_kernel(
    const u16* __restrict__ X, const u16* __restrict__ Wt,
    const u16* __restrict__ b0, const u16* __restrict__ b1, const u16* __restrict__ b2,
    void* __restrict__ o0, u16* __restrict__ o1, u16* __restrict__ o2,
    const int* __restrict__ flag) {
  __shared__ alignas(16) u16 As[128 * 32];
  __shared__ alignas(16) u16 Bs[128 * 32];
  const int tid = threadIdx.x;
  const int wave = tid >> 6, lane = tid & 63;
  const int m0 = blockIdx.y * 128, n0 = blockIdx.x * 128;
  const int wm = (wave >> 1) * 64, wn = (wave & 1) * 64;
  const int fr = lane & 15, fq = lane >> 4;

  f32x4 acc[4][4] = {};

  const int s0 = tid, s1 = 256 + tid;
  const u16* gA0 = X + (m0 + (s0 >> 2)) * 1024 + (s0 & 3) * 8;
  const u16* gA1 = X + (m0 + (s1 >> 2)) * 1024 + (s1 & 3) * 8;
  const u16* gB0 = Wt + (n0 + (s0 >> 2)) * 1024 + (s0 & 3) * 8;
  const u16* gB1 = Wt + (n0 + (s1 >> 2)) * 1024 + (s1 & 3) * 8;
  u16* lA0 = As + wave * 64 * 8;
  u16* lA1 = As + (256 + wave * 64) * 8;
  u16* lB0 = Bs + wave * 64 * 8;
  u16* lB1 = Bs + (256 + wave * 64) * 8;
  const u16* aRd = As + (wm + fr) * 32 + fq * 8;
  const u16* bRd = Bs + (wn + fr) * 32 + fq * 8;

  for (int kb = 0; kb < 32; ++kb) {
    const int ko = kb * 32;
    if (kb) __syncthreads();
    async16(gA0 + ko, lA0);
    async16(gA1 + ko, lA1);
    async16(gB0 + ko, lB0);
    async16(gB1 + ko, lB1);
    __syncthreads();  // compiler emits s_waitcnt vmcnt(0) before s_barrier
    bf16x8 af[4], bfr[4];
#pragma unroll
    for (int t = 0; t < 4; ++t) af[t] = ld_frag(aRd + t * 16 * 32);
#pragma unroll
    for (int t = 0; t < 4; ++t) bfr[t] = ld_frag(bRd + t * 16 * 32);
#pragma unroll
    for (int i = 0; i < 4; ++i)
#pragma unroll
      for (int j = 0; j < 4; ++j) acc[i][j] = MFMA16(af[i], bfr[j], acc[i][j]);
  }

  const int c = fr, g = fq;
  if (MODE == 0) {
    const int q = n0 >> 10;  // 0=Q,1=K,2=V
    const int nb = (n0 & 1023) + wn;
    const u16* bp = (q == 0) ? b0 : ((q == 1) ? b1 : b2);
    u16* q0 = (u16*)o0;
#pragma unroll
    for (int tm = 0; tm < 4; ++tm) {
      const int mbase = m0 + wm + tm * 16;
      const int bidx = mbase >> 4;
#pragma unroll
      for (int tn = 0; tn < 4; ++tn) {
        const int nl = nb + tn * 16 + c;
        const int h = nl >> 6, d = nl & 63;
        const float bias = bf2f(bp[nl]);
        const int bh = bidx * 16 + h;
        if (q == 2) {
          // j = g*4+r contiguous -> one 8B store per lane
          u16x4 pk;
#pragma unroll
          for (int r = 0; r < 4; ++r) pk[r] = f2bf(acc[tm][tn][r] + bias);
          *reinterpret_cast<u16x4*>(&o2[(bh * 64 + d) * 16 + g * 4]) = pk;
        } else {
          u16* dstq = (q == 0) ? q0 : o1;
#pragma unroll
          for (int r = 0; r < 4; ++r) {
            const int j = g * 4 + r;
            dstq[(bh * 16 + j) * 64 + d] = f2bf(acc[tm][tn][r] + bias);
          }
        }
      }
    }
  } else {
    const int isf32 = *flag;
#pragma unroll
    for (int tm = 0; tm < 4; ++tm) {
      const int m = m0 + wm + tm * 16 + g * 4;
#pragma unroll
      for (int tn = 0; tn < 4; ++tn) {
        const int n = n0 + wn + tn * 16 + c;
        const float bias = bf2f(b0[n]);
        if (isf32) {
#pragma unroll
          for (int r = 0; r < 4; ++r)
            ((float*)o0)[(m + r) * 1024 + n] = acc[tm][tn][r] + bias;
        } else {
#pragma unroll
          for (int r = 0; r < 4; ++r)
            ((u16*)o0)[(m + r) * 1024 + n] = f2bf(acc[tm][tn][r] + bias);
        }
      }
    }
  }
}

// ---------------- attention: one wave per (b,h), irreps batched x4 -----------
// S = s*QK^T -> LDS as S^T (B-operand form, reused for all p)
// per group of 4 p: A_p = P_p@S ; B_p = A_p@P_p^T ; softmax (no max-sub:
// scores are O(+-10), exp can't overflow fp32, softmax shift-invariant);
// M += w@P_p accumulated in AGPRs.  out = M @ V via Vt.
// Batching gives 4-wide ILP between lgkmcnt(0) drains: 16 drains/wave vs 48.
__global__ __launch_bounds__(256) void attn_kernel(
    const u16* __restrict__ Qb, const u16* __restrict__ Kb, const u16* __restrict__ Vt,
    const u16* __restrict__ P, u16* __restrict__ Tb) {
  __shared__ alignas(16) u16 Pl[4096];   // P[p][i][j]
  __shared__ alignas(16) u16 Ptl[4096];  // P^T
  __shared__ alignas(16) u16 STl[4][16 * 24];
  __shared__ alignas(16) u16 CVl[4][4][16 * 24];  // [wave][slot]

  const int tid = threadIdx.x;
#pragma unroll
  for (int i = 0; i < 16; ++i) {
    const int idx = i * 256 + tid;
    const u16 v = P[idx];
    Pl[idx] = v;
    const int p = idx >> 8, rc = idx & 255, rr = rc >> 4, cc = rc & 15;
    Ptl[(p << 8) + (cc << 4) + rr] = v;
  }
  __syncthreads();

  const int wave = tid >> 6, lane = tid & 63;
  const int bh = blockIdx.x * 4 + wave;
  const int fr = lane & 15, fq = lane >> 4;
  const int c = fr, g = fq;
  u16* ST = STl[wave];

  const u16* qb = Qb + bh * 1024;
  const u16* kb = Kb + bh * 1024;
  const u16* vb = Vt + bh * 1024;

  const bf16x8 qf0 = ld_frag(qb + fr * 64 + fq * 8);
  const bf16x8 qf1 = ld_frag(qb + fr * 64 + 32 + fq * 8);
  const bf16x8 kf0 = ld_frag(kb + fr * 64 + fq * 8);
  const bf16x8 kf1 = ld_frag(kb + fr * 64 + 32 + fq * 8);
  f32x4 S = {0.f, 0.f, 0.f, 0.f};
  S = MFMA16(qf0, kf0, S);
  S = MFMA16(qf1, kf1, S);
  const float scale = 0.125f;  // 1/sqrt(64)

#pragma unroll
  for (int r = 0; r < 4; ++r) ST[c * 24 + g * 4 + r] = f2bf(S[r] * scale);
  lds_fence();
  const bf16x8 sf = ld_frag_lo(ST + fr * 24 + fq * 8, lane);

  f32x4 Macc = {0.f, 0.f, 0.f, 0.f};
  for (int pg = 0; pg < 4; ++pg) {
    const int pbase = pg * 4;
    bf16x8 pa[4];
    f32x4 Ap[4];
#pragma unroll
    for (int q = 0; q < 4; ++q)
      pa[q] = ld_frag_lo(Pl + ((pbase + q) << 8) + fr * 16 + fq * 8, lane);
#pragma unroll
    for (int q = 0; q < 4; ++q) {
      f32x4 z = {0.f, 0.f, 0.f, 0.f};
      Ap[q] = MFMA16(pa[q], sf, z);
    }
#pragma unroll
    for (int q = 0; q < 4; ++q)
#pragma unroll
      for (int r = 0; r < 4; ++r)
        CVl[wave][q][(g * 4 + r) * 24 + c] = f2bf(Ap[q][r]);
    lds_fence();
    bf16x8 aa[4];
#pragma unroll
    for (int q = 0; q < 4; ++q)
      aa[q] = ld_frag_lo(CVl[wave][q] + fr * 24 + fq * 8, lane);
    f32x4 Bp[4];
#pragma unroll
    for (int q = 0; q < 4; ++q) {
      f32x4 z = {0.f, 0.f, 0.f, 0.f};
      Bp[q] = MFMA16(aa[q], pa[q], z);
    }
    float w[4][4];
#pragma unroll
    for (int q = 0; q < 4; ++q)
#pragma unroll
      for (int r = 0; r < 4; ++r) {
        const float e = __expf(Bp[q][r]);
        float sm = e;
        sm += __shfl_xor(sm, 1);
        sm += __shfl_xor(sm, 2);
        sm += __shfl_xor(sm, 4);
        sm += __shfl_xor(sm, 8);
        w[q][r] = e / sm;
      }
    lds_fence();  // aa reads drained before overwriting CV
#pragma unroll
    for (int q = 0; q < 4; ++q)
#pragma unroll
      for (int r = 0; r < 4; ++r)
        CVl[wave][q][(g * 4 + r) * 24 + c] = f2bf(w[q][r]);
    lds_fence();
#pragma unroll
    for (int q = 0; q < 4; ++q) {
      const bf16x8 wa = ld_frag_lo(CVl[wave][q] + fr * 24 + fq * 8, lane);
      const bf16x8 pb = ld_frag_lo(Ptl + ((pbase + q) << 8) + fr * 16 + fq * 8, lane);
      Macc = MFMA16(wa, pb, Macc);
    }
    lds_fence();  // wa reads drained before next group's A_p stores
  }

#pragma unroll
  for (int r = 0; r < 4; ++r) CVl[wave][0][(g * 4 + r) * 24 + c] = f2bf(Macc[r]);
  lds_fence();
  const bf16x8 ma = ld_frag_lo(CVl[wave][0] + fr * 24 + fq * 8, lane);

  const int b = bh >> 4, h = bh & 15;
  u16* outp = Tb + (b * 16) * 1024 + h * 64;
#pragma unroll
  for (int dt = 0; dt < 4; ++dt) {
    const bf16x8 vf = ld_frag_lo(vb + (dt * 16 + fr) * 16 + fq * 8, lane);
    f32x4 o = {0.f, 0.f, 0.f, 0.f};
    o = MFMA16(ma, vf, o);
#pragma unroll
    for (int r = 0; r < 4; ++r)
      outp[(g * 4 + r) * 1024 + dt * 16 + c] = f2bf(o[r]);
  }
}

// ---------------- launcher ---------------------------------------------------
extern "C" void kernel_launch(void* const* d_in, const int* in_sizes, int n_in,
                              void* d_out, int out_size, void* d_ws, size_t ws_size,
                              hipStream_t stream) {
  const void* x = d_in[0];
  const void* proj = d_in[1];
  const void* Wq = d_in[2];
  const void* bq = d_in[3];
  const void* Wk = d_in[4];
  const void* bk = d_in[5];
  const void* Wv = d_in[6];
  const void* bv = d_in[7];
  const void* Wo = d_in[8];
  const void* bo = d_in[9];

  char* ws = (char*)d_ws;
  int* flag = (int*)ws;          ws += 256;
  u16* bqc  = (u16*)ws;          ws += 1024 * 2;
  u16* bkc  = (u16*)ws;          ws += 1024 * 2;
  u16* bvc  = (u16*)ws;          ws += 1024 * 2;
  u16* boc  = (u16*)ws;          ws += 1024 * 2;
  u16* pjc  = (u16*)ws;          ws += 4096 * 2;
  u16* WtQKV = (u16*)ws;         ws += (size_t)3072 * 1024 * 2;
  u16* WtO   = (u16*)ws;         ws += (size_t)1024 * 1024 * 2;
  u16* Xb    = (u16*)ws;         ws += (size_t)16384 * 1024 * 2;
  u16* Qbuf  = (u16*)ws;         ws += (size_t)16384 * 1024 * 2;
  u16* Kbuf  = (u16*)ws;         ws += (size_t)16384 * 1024 * 2;
  u16* Vtb   = (u16*)ws;         ws += (size_t)16384 * 1024 * 2;
  u16* Tbuf  = (u16*)ws;         ws += (size_t)16384 * 1024 * 2;

  detect_dtype<<<1, 256, 0, stream>>>((const u32*)x, flag);

  convert_bf16<<<8192, 256, 0, stream>>>(x, Xb, 16777216, flag);
  convert_bf16<<<1, 256, 0, stream>>>(bq, bqc, 1024, flag);
  convert_bf16<<<1, 256, 0, stream>>>(bk, bkc, 1024, flag);
  convert_bf16<<<1, 256, 0, stream>>>(bv, bvc, 1024, flag);
  convert_bf16<<<1, 256, 0, stream>>>(bo, boc, 1024, flag);
  convert_bf16<<<2, 256, 0, stream>>>(proj, pjc, 4096, flag);

  const dim3 tg(32, 32);
  transpose_conv<<<tg, 256, 0, stream>>>(Wq, WtQKV, flag);
  transpose_conv<<<tg, 256, 0, stream>>>(Wk, WtQKV + 1024 * 1024, flag);
  transpose_conv<<<tg, 256, 0, stream>>>(Wv, WtQKV + 2 * 1024 * 1024, flag);
  transpose_conv<<<tg, 256, 0, stream>>>(Wo, WtO, flag);

  gemm_kernel<0><<<dim3(24, 128), 256, 0, stream>>>(Xb, WtQKV, bqc, bkc, bvc,
                                                    Qbuf, Kbuf, Vtb, nullptr);
  attn_kernel<<<4096, 256, 0, stream>>>(Qbuf, Kbuf, Vtb, pjc, Tbuf);
  gemm_kernel<1><<<dim3(8, 128), 256, 0, stream>>>(Tbuf, WtO, boc, nullptr, nullptr,
                                                   d_out, nullptr, nullptr, flag);
}

// Round 5
// 405.917 us; speedup vs baseline: 1.2976x; 1.0803x over previous
//
#include <hip/hip_runtime.h>

// PSEAD attention. Math: scores_p = P_p (s*QK^T) P_p^T ;
// out_bh = (sum_p softmax(scores_p) P_p) V
// Dtype-adaptive (fp32/bf16 inputs), all-bf16 MFMA pipeline.
// Attention computed fully in transposed form so every layout conversion is
// the cheap one (C-layout -> B-operand / transposed-A) via 4 shuffles, no LDS.

typedef unsigned short u16;
typedef unsigned int u32;
typedef __attribute__((ext_vector_type(8))) __bf16 bf16x8;
typedef __attribute__((ext_vector_type(4))) float f32x4;
typedef __attribute__((ext_vector_type(4))) u32 u32x4;
typedef __attribute__((ext_vector_type(4))) u16 u16x4;
typedef __attribute__((ext_vector_type(4))) float float4v;
typedef __attribute__((address_space(1))) void gvoid;
typedef __attribute__((address_space(3))) void svoid;

#define MFMA16(a, b, c) __builtin_amdgcn_mfma_f32_16x16x32_bf16(a, b, c, 0, 0, 0)

__device__ __forceinline__ u16 f2bf(float f) {
  u32 u = __builtin_bit_cast(u32, f);
  return (u16)((u + 0x7fffu + ((u >> 16) & 1u)) >> 16);
}
__device__ __forceinline__ float bf2f(u16 h) {
  u32 u = ((u32)h) << 16;
  return __builtin_bit_cast(float, u);
}
__device__ __forceinline__ bf16x8 ld_frag(const u16* p) {
  u32x4 v = *reinterpret_cast<const u32x4*>(p);
  return __builtin_bit_cast(bf16x8, v);
}
// K=16 padded to K=32: lanes >= 32 supply zeros
__device__ __forceinline__ bf16x8 ld_frag_lo(const u16* p, int lane) {
  u32x4 v = {0u, 0u, 0u, 0u};
  if (lane < 32) v = *reinterpret_cast<const u32x4*>(p);
  return __builtin_bit_cast(bf16x8, v);
}
__device__ __forceinline__ void async16(const u16* g, u16* l) {
  __builtin_amdgcn_global_load_lds((gvoid*)g, (svoid*)l, 16, 0, 0);
}

// C-layout f32x4 -> bf16 fragment holding X-as-B-operand (== X^T-as-A-operand).
// C-layout: X[row][col] at lane col+16*(row>>2), reg row&3.
// B-frag: lane l gives B[k][n], n=l&15, k=(l>>4)*8+j  (lanes>=32 -> k>=16: zero).
// dst reg t (k=2t,2t+1): src lane (l&15)+32*((l>>4)&1)+16*(t>>1), regs (2t&3,+1).
__device__ __forceinline__ bf16x8 c2frag(f32x4 v, int lane) {
  const u32 p01 = ((u32)f2bf(v[1]) << 16) | (u32)f2bf(v[0]);
  const u32 p23 = ((u32)f2bf(v[3]) << 16) | (u32)f2bf(v[2]);
  const int base = (lane & 15) + ((lane & 16) << 1);
  u32x4 o;
  o[0] = (u32)__shfl((int)p01, base);
  o[1] = (u32)__shfl((int)p23, base);
  o[2] = (u32)__shfl((int)p01, base + 16);
  o[3] = (u32)__shfl((int)p23, base + 16);
  if (lane >= 32) o = (u32x4){0u, 0u, 0u, 0u};
  return __builtin_bit_cast(bf16x8, o);
}

// --------- setup: dtype detect + small tensors (biases, projectors) ---------
__global__ __launch_bounds__(256) void setup_small(
    const void* __restrict__ x, const void* __restrict__ proj,
    const void* __restrict__ bq, const void* __restrict__ bk,
    const void* __restrict__ bv, const void* __restrict__ bo,
    int* __restrict__ flag, u16* __restrict__ pjc, u16* __restrict__ bqc,
    u16* __restrict__ bkc, u16* __restrict__ bvc, u16* __restrict__ boc) {
  const int tid = threadIdx.x;
  int cnt = 0;
  const u32* xw = (const u32*)x;
  for (int i = tid; i < 16384; i += 256) {
    const u32 e = (xw[i] >> 23) & 0xffu;
    cnt += (e >= 64u && e <= 191u) ? 1 : 0;
  }
  __shared__ int sred[4];
  for (int o = 32; o; o >>= 1) cnt += __shfl_down(cnt, o);
  if ((tid & 63) == 0) sred[tid >> 6] = cnt;
  __shared__ int sflag;
  __syncthreads();
  if (tid == 0) {
    const int f = (sred[0] + sred[1] + sred[2] + sred[3] > 8192) ? 1 : 0;
    sflag = f;
    flag[0] = f;  // 1 = fp32
  }
  __syncthreads();
  const int isf32 = sflag;
  const void* srcs[5] = {proj, bq, bk, bv, bo};
  u16* dsts[5] = {pjc, bqc, bkc, bvc, boc};
  const int ns[5] = {4096, 1024, 1024, 1024, 1024};
#pragma unroll
  for (int t = 0; t < 5; ++t) {
    for (int i = tid; i < ns[t]; i += 256)
      dsts[t][i] = isf32 ? f2bf(((const float*)srcs[t])[i]) : ((const u16*)srcs[t])[i];
  }
}

// --------- canonicalize x: coalesced float4/u16x4 ---------------------------
__global__ __launch_bounds__(256) void convert_x(const void* __restrict__ src,
                                                 u16* __restrict__ dst,
                                                 const int* __restrict__ flag) {
  const int i4 = blockIdx.x * 256 + threadIdx.x;  // 4 elems per thread
  if (*flag) {
    const float4v v = ((const float4v*)src)[i4];
    u16x4 o;
#pragma unroll
    for (int j = 0; j < 4; ++j) o[j] = f2bf(v[j]);
    ((u16x4*)dst)[i4] = o;
  } else {
    ((u16x4*)dst)[i4] = ((const u16x4*)src)[i4];
  }
}

// --------- weight transpose+convert: dst[n][k] = bf16(src[k][n]), z picks W --
__global__ __launch_bounds__(256) void transpose_conv(
    const void* __restrict__ w0, const void* __restrict__ w1,
    const void* __restrict__ w2, const void* __restrict__ w3,
    u16* __restrict__ d0, u16* __restrict__ d1, u16* __restrict__ d2,
    u16* __restrict__ d3, const int* __restrict__ flag) {
  __shared__ u16 tile[32][33];
  const int z = blockIdx.z;
  const void* src = (z == 0) ? w0 : (z == 1) ? w1 : (z == 2) ? w2 : w3;
  u16* dst = (z == 0) ? d0 : (z == 1) ? d1 : (z == 2) ? d2 : d3;
  const int isf32 = *flag;
  const int tx = threadIdx.x & 31;
  const int ty = (threadIdx.x >> 5) * 4;
  const int bx = blockIdx.x * 32;
  const int by = blockIdx.y * 32;
#pragma unroll
  for (int r = 0; r < 4; ++r) {
    const int idx = (by + ty + r) * 1024 + bx + tx;
    tile[ty + r][tx] = isf32 ? f2bf(((const float*)src)[idx]) : ((const u16*)src)[idx];
  }
  __syncthreads();
#pragma unroll
  for (int r = 0; r < 4; ++r)
    dst[(bx + ty + r) * 1024 + by + tx] = tile[tx][ty + r];
}

// ---------------- 128x128x(BK=32) bf16 MFMA GEMM, m97-style ------------------
// MODE 0: X[16384x1024] @ WtQKV^T -> scatter Q[bh][j][64], K[bh][j][64], Vt[bh][64][16]
// MODE 1: T[16384x1024] @ WtO^T + bo -> out[16384][1024] (fp32 or bf16 per flag)
template <int MODE>
__global__ __launch_bounds__(256) void gemm_kernel(
    const u16* __restrict__ X, const u16* __restrict__ Wt,
    const u16* __restrict__ b0, const u16* __restrict__ b1, const u16* __restrict__ b2,
    void* __restrict__ o0, u16* __restrict__ o1, u16* __restrict__ o2,
    const int* __restrict__ flag) {
  __shared__ alignas(16) u16 As[128 * 32];
  __shared__ alignas(16) u16 Bs[128 * 32];
  const int tid = threadIdx.x;
  const int wave = tid >> 6, lane = tid & 63;
  const int m0 = blockIdx.y * 128, n0 = blockIdx.x * 128;
  const int wm = (wave >> 1) * 64, wn = (wave & 1) * 64;
  const int fr = lane & 15, fq = lane >> 4;

  f32x4 acc[4][4] = {};

  const int s0 = tid, s1 = 256 + tid;
  const u16* gA0 = X + (m0 + (s0 >> 2)) * 1024 + (s0 & 3) * 8;
  const u16* gA1 = X + (m0 + (s1 >> 2)) * 1024 + (s1 & 3) * 8;
  const u16* gB0 = Wt + (n0 + (s0 >> 2)) * 1024 + (s0 & 3) * 8;
  const u16* gB1 = Wt + (n0 + (s1 >> 2)) * 1024 + (s1 & 3) * 8;
  u16* lA0 = As + wave * 64 * 8;
  u16* lA1 = As + (256 + wave * 64) * 8;
  u16* lB0 = Bs + wave * 64 * 8;
  u16* lB1 = Bs + (256 + wave * 64) * 8;
  const u16* aRd = As + (wm + fr) * 32 + fq * 8;
  const u16* bRd = Bs + (wn + fr) * 32 + fq * 8;

  for (int kb = 0; kb < 32; ++kb) {
    const int ko = kb * 32;
    if (kb) __syncthreads();
    async16(gA0 + ko, lA0);
    async16(gA1 + ko, lA1);
    async16(gB0 + ko, lB0);
    async16(gB1 + ko, lB1);
    __syncthreads();  // compiler emits s_waitcnt vmcnt(0) before s_barrier
    bf16x8 af[4], bfr[4];
#pragma unroll
    for (int t = 0; t < 4; ++t) af[t] = ld_frag(aRd + t * 16 * 32);
#pragma unroll
    for (int t = 0; t < 4; ++t) bfr[t] = ld_frag(bRd + t * 16 * 32);
#pragma unroll
    for (int i = 0; i < 4; ++i)
#pragma unroll
      for (int j = 0; j < 4; ++j) acc[i][j] = MFMA16(af[i], bfr[j], acc[i][j]);
  }

  const int c = fr, g = fq;
  if (MODE == 0) {
    const int q = n0 >> 10;  // 0=Q,1=K,2=V
    const int nb = (n0 & 1023) + wn;
    const u16* bp = (q == 0) ? b0 : ((q == 1) ? b1 : b2);
    u16* q0 = (u16*)o0;
#pragma unroll
    for (int tm = 0; tm < 4; ++tm) {
      const int mbase = m0 + wm + tm * 16;
      const int bidx = mbase >> 4;
#pragma unroll
      for (int tn = 0; tn < 4; ++tn) {
        const int nl = nb + tn * 16 + c;
        const int h = nl >> 6, d = nl & 63;
        const float bias = bf2f(bp[nl]);
        const int bh = bidx * 16 + h;
        if (q == 2) {
          u16x4 pk;
#pragma unroll
          for (int r = 0; r < 4; ++r) pk[r] = f2bf(acc[tm][tn][r] + bias);
          *reinterpret_cast<u16x4*>(&o2[(bh * 64 + d) * 16 + g * 4]) = pk;
        } else {
          u16* dstq = (q == 0) ? q0 : o1;
#pragma unroll
          for (int r = 0; r < 4; ++r) {
            const int j = g * 4 + r;
            dstq[(bh * 16 + j) * 64 + d] = f2bf(acc[tm][tn][r] + bias);
          }
        }
      }
    }
  } else {
    const int isf32 = *flag;
#pragma unroll
    for (int tm = 0; tm < 4; ++tm) {
      const int m = m0 + wm + tm * 16 + g * 4;
#pragma unroll
      for (int tn = 0; tn < 4; ++tn) {
        const int n = n0 + wn + tn * 16 + c;
        const float bias = bf2f(b0[n]);
        if (isf32) {
#pragma unroll
          for (int r = 0; r < 4; ++r)
            ((float*)o0)[(m + r) * 1024 + n] = acc[tm][tn][r] + bias;
        } else {
#pragma unroll
          for (int r = 0; r < 4; ++r)
            ((u16*)o0)[(m + r) * 1024 + n] = f2bf(acc[tm][tn][r] + bias);
        }
      }
    }
  }
}

// ---------------- attention: one wave per (b,h), transposed chain ------------
// S = QK^T (C-layout); St frag = c2frag(S*scale) once (== S^T as A-operand).
// Per irrep p (all operand transforms are register shuffles, no LDS traffic):
//   A_p^T = St . (Pl_p as B = P_p^T)            -> C-layout
//   B_p^T = (Pl_p as A = P_p) . c2frag(A_p^T)   -> scores^T, C-layout (row=j)
//   softmax over j = in-lane 4 regs + shfl_xor(16,32)
//   M^T  += (Ptl_p as A = P_p^T) . c2frag(w^T)  -> AGPR accumulate
// Epilogue: O^T tile = (Vt rows as A = V^T) . c2frag(M^T); 8B stores.
__global__ __launch_bounds__(256) void attn_kernel(
    const u16* __restrict__ Qb, const u16* __restrict__ Kb, const u16* __restrict__ Vt,
    const u16* __restrict__ P, u16* __restrict__ Tb) {
  __shared__ alignas(16) u16 Pl[4096];   // P[p][i][j]
  __shared__ alignas(16) u16 Ptl[4096];  // P^T
  const int tid = threadIdx.x;
#pragma unroll
  for (int i = 0; i < 16; ++i) {
    const int idx = i * 256 + tid;
    const u16 v = P[idx];
    Pl[idx] = v;
    const int p = idx >> 8, rc = idx & 255, rr = rc >> 4, cc = rc & 15;
    Ptl[(p << 8) + (cc << 4) + rr] = v;
  }
  __syncthreads();

  const int wave = tid >> 6, lane = tid & 63;
  const int bh = blockIdx.x * 4 + wave;
  const int fr = lane & 15, fq = lane >> 4;

  const u16* qb = Qb + bh * 1024;
  const u16* kb = Kb + bh * 1024;
  const u16* vb = Vt + bh * 1024;

  const bf16x8 qf0 = ld_frag(qb + fr * 64 + fq * 8);
  const bf16x8 qf1 = ld_frag(qb + fr * 64 + 32 + fq * 8);
  const bf16x8 kf0 = ld_frag(kb + fr * 64 + fq * 8);
  const bf16x8 kf1 = ld_frag(kb + fr * 64 + 32 + fq * 8);
  f32x4 S = {0.f, 0.f, 0.f, 0.f};
  S = MFMA16(qf0, kf0, S);
  S = MFMA16(qf1, kf1, S);
#pragma unroll
  for (int r = 0; r < 4; ++r) S[r] *= 0.125f;  // 1/sqrt(64)
  const bf16x8 St = c2frag(S, lane);  // S^T as A-operand, reused all irreps

  f32x4 Mt = {0.f, 0.f, 0.f, 0.f};
#pragma unroll 4
  for (int p = 0; p < 16; ++p) {
    const bf16x8 pl = ld_frag_lo(Pl + (p << 8) + fr * 16 + fq * 8, lane);
    const bf16x8 pt = ld_frag_lo(Ptl + (p << 8) + fr * 16 + fq * 8, lane);
    f32x4 z = {0.f, 0.f, 0.f, 0.f};
    const f32x4 ApT = MFMA16(St, pl, z);            // S^T P_p^T = (P_p S)^T
    const f32x4 BpT = MFMA16(pl, c2frag(ApT, lane), z);  // P_p A_p^T = scores^T
    float e[4], s = 0.f;
#pragma unroll
    for (int r = 0; r < 4; ++r) {
      e[r] = __expf(BpT[r]);
      s += e[r];
    }
    s += __shfl_xor(s, 16);
    s += __shfl_xor(s, 32);
    const float rs = __frcp_rn(s);
    f32x4 w;
#pragma unroll
    for (int r = 0; r < 4; ++r) w[r] = e[r] * rs;
    Mt = MFMA16(pt, c2frag(w, lane), Mt);           // P_p^T w^T = (w P_p)^T
  }

  const bf16x8 mb = c2frag(Mt, lane);  // M^T as B-operand

  const int b = bh >> 4, h = bh & 15;
  u16* outp = Tb + (b * 16 + fr) * 1024 + h * 64;  // fr = i (C-layout col)
#pragma unroll
  for (int dt = 0; dt < 4; ++dt) {
    const bf16x8 vf = ld_frag_lo(vb + (dt * 16 + fr) * 16 + fq * 8, lane);  // V^T rows
    f32x4 z = {0.f, 0.f, 0.f, 0.f};
    const f32x4 ot = MFMA16(vf, mb, z);  // V^T M^T = O^T tile: row=d, col=i
    u16x4 pk;
#pragma unroll
    for (int r = 0; r < 4; ++r) pk[r] = f2bf(ot[r]);
    *reinterpret_cast<u16x4*>(&outp[dt * 16 + fq * 4]) = pk;  // d contiguous
  }
}

// ---------------- launcher ---------------------------------------------------
extern "C" void kernel_launch(void* const* d_in, const int* in_sizes, int n_in,
                              void* d_out, int out_size, void* d_ws, size_t ws_size,
                              hipStream_t stream) {
  const void* x = d_in[0];
  const void* proj = d_in[1];
  const void* Wq = d_in[2];
  const void* bq = d_in[3];
  const void* Wk = d_in[4];
  const void* bk = d_in[5];
  const void* Wv = d_in[6];
  const void* bv = d_in[7];
  const void* Wo = d_in[8];
  const void* bo = d_in[9];

  char* ws = (char*)d_ws;
  int* flag = (int*)ws;          ws += 256;
  u16* bqc  = (u16*)ws;          ws += 1024 * 2;
  u16* bkc  = (u16*)ws;          ws += 1024 * 2;
  u16* bvc  = (u16*)ws;          ws += 1024 * 2;
  u16* boc  = (u16*)ws;          ws += 1024 * 2;
  u16* pjc  = (u16*)ws;          ws += 4096 * 2;
  u16* WtQKV = (u16*)ws;         ws += (size_t)3072 * 1024 * 2;
  u16* WtO   = (u16*)ws;         ws += (size_t)1024 * 1024 * 2;
  u16* Xb    = (u16*)ws;         ws += (size_t)16384 * 1024 * 2;
  u16* Qbuf  = (u16*)ws;         ws += (size_t)16384 * 1024 * 2;
  u16* Kbuf  = (u16*)ws;         ws += (size_t)16384 * 1024 * 2;
  u16* Vtb   = (u16*)ws;         ws += (size_t)16384 * 1024 * 2;
  u16* Tbuf  = (u16*)ws;         ws += (size_t)16384 * 1024 * 2;

  setup_small<<<1, 256, 0, stream>>>(x, proj, bq, bk, bv, bo, flag, pjc, bqc, bkc,
                                     bvc, boc);
  convert_x<<<16384, 256, 0, stream>>>(x, Xb, flag);
  transpose_conv<<<dim3(32, 32, 4), 256, 0, stream>>>(
      Wq, Wk, Wv, Wo, WtQKV, WtQKV + 1024 * 1024, WtQKV + 2 * 1024 * 1024, WtO, flag);

  gemm_kernel<0><<<dim3(24, 128), 256, 0, stream>>>(Xb, WtQKV, bqc, bkc, bvc,
                                                    Qbuf, Kbuf, Vtb, nullptr);
  attn_kernel<<<4096, 256, 0, stream>>>(Qbuf, Kbuf, Vtb, pjc, Tbuf);
  gemm_kernel<1><<<dim3(8, 128), 256, 0, stream>>>(Tbuf, WtO, boc, nullptr, nullptr,
                                                   d_out, nullptr, nullptr, flag);
}

// Round 6
// 388.253 us; speedup vs baseline: 1.3566x; 1.0455x over previous
//
#include <hip/hip_runtime.h>

// PSEAD attention. Math: scores_p = P_p (s*QK^T) P_p^T ;
// out_bh = (sum_p softmax(scores_p) P_p) V
// Dtype-adaptive (fp32/bf16 inputs), all-bf16 MFMA pipeline.
// R6: QKV GEMM BK=64 (half the barrier drains; out-GEMM stays BK=32 as A/B
// control); setup_small removed (parallel detect; bias/proj convert inlined
// into consumers).

typedef unsigned short u16;
typedef unsigned int u32;
typedef __attribute__((ext_vector_type(8))) __bf16 bf16x8;
typedef __attribute__((ext_vector_type(4))) float f32x4;
typedef __attribute__((ext_vector_type(4))) u32 u32x4;
typedef __attribute__((ext_vector_type(4))) u16 u16x4;
typedef __attribute__((ext_vector_type(4))) float float4v;
typedef __attribute__((address_space(1))) void gvoid;
typedef __attribute__((address_space(3))) void svoid;

#define MFMA16(a, b, c) __builtin_amdgcn_mfma_f32_16x16x32_bf16(a, b, c, 0, 0, 0)

__device__ __forceinline__ u16 f2bf(float f) {
  u32 u = __builtin_bit_cast(u32, f);
  return (u16)((u + 0x7fffu + ((u >> 16) & 1u)) >> 16);
}
__device__ __forceinline__ float bf2f(u16 h) {
  u32 u = ((u32)h) << 16;
  return __builtin_bit_cast(float, u);
}
__device__ __forceinline__ float ld_bias(const void* p, int i, int isf32) {
  return isf32 ? ((const float*)p)[i] : bf2f(((const u16*)p)[i]);
}
__device__ __forceinline__ bf16x8 ld_frag(const u16* p) {
  u32x4 v = *reinterpret_cast<const u32x4*>(p);
  return __builtin_bit_cast(bf16x8, v);
}
// K=16 padded to K=32: lanes >= 32 supply zeros
__device__ __forceinline__ bf16x8 ld_frag_lo(const u16* p, int lane) {
  u32x4 v = {0u, 0u, 0u, 0u};
  if (lane < 32) v = *reinterpret_cast<const u32x4*>(p);
  return __builtin_bit_cast(bf16x8, v);
}
__device__ __forceinline__ void async16(const u16* g, u16* l) {
  __builtin_amdgcn_global_load_lds((gvoid*)g, (svoid*)l, 16, 0, 0);
}

// C-layout f32x4 -> bf16 fragment holding X-as-B-operand (== X^T-as-A-operand).
__device__ __forceinline__ bf16x8 c2frag(f32x4 v, int lane) {
  const u32 p01 = ((u32)f2bf(v[1]) << 16) | (u32)f2bf(v[0]);
  const u32 p23 = ((u32)f2bf(v[3]) << 16) | (u32)f2bf(v[2]);
  const int base = (lane & 15) + ((lane & 16) << 1);
  u32x4 o;
  o[0] = (u32)__shfl((int)p01, base);
  o[1] = (u32)__shfl((int)p23, base);
  o[2] = (u32)__shfl((int)p01, base + 16);
  o[3] = (u32)__shfl((int)p23, base + 16);
  if (lane >= 32) o = (u32x4){0u, 0u, 0u, 0u};
  return __builtin_bit_cast(bf16x8, o);
}

// --------- dtype detect: fp32 u32-exponents cluster in [64,191] -------------
__global__ __launch_bounds__(1024) void detect_dtype(const u32* __restrict__ x,
                                                     int* __restrict__ flag) {
  const int tid = threadIdx.x;
  int cnt = 0;
#pragma unroll
  for (int q = 0; q < 4; ++q) {
    const u32x4 v = ((const u32x4*)x)[q * 1024 + tid];
#pragma unroll
    for (int j = 0; j < 4; ++j) {
      const u32 e = (v[j] >> 23) & 0xffu;
      cnt += (e >= 64u && e <= 191u) ? 1 : 0;
    }
  }
  __shared__ int sred[16];
  for (int o = 32; o; o >>= 1) cnt += __shfl_down(cnt, o);
  if ((tid & 63) == 0) sred[tid >> 6] = cnt;
  __syncthreads();
  if (tid == 0) {
    int t = 0;
#pragma unroll
    for (int i = 0; i < 16; ++i) t += sred[i];
    flag[0] = (t > 8192) ? 1 : 0;  // 1 = fp32
  }
}

// --------- canonicalize x: coalesced float4/u16x4 ---------------------------
__global__ __launch_bounds__(256) void convert_x(const void* __restrict__ src,
                                                 u16* __restrict__ dst,
                                                 const int* __restrict__ flag) {
  const int i4 = blockIdx.x * 256 + threadIdx.x;  // 4 elems per thread
  if (*flag) {
    const float4v v = ((const float4v*)src)[i4];
    u16x4 o;
#pragma unroll
    for (int j = 0; j < 4; ++j) o[j] = f2bf(v[j]);
    ((u16x4*)dst)[i4] = o;
  } else {
    ((u16x4*)dst)[i4] = ((const u16x4*)src)[i4];
  }
}

// --------- weight transpose+convert: dst[n][k] = bf16(src[k][n]), z picks W --
__global__ __launch_bounds__(256) void transpose_conv(
    const void* __restrict__ w0, const void* __restrict__ w1,
    const void* __restrict__ w2, const void* __restrict__ w3,
    u16* __restrict__ d0, u16* __restrict__ d1, u16* __restrict__ d2,
    u16* __restrict__ d3, const int* __restrict__ flag) {
  __shared__ u16 tile[32][33];
  const int z = blockIdx.z;
  const void* src = (z == 0) ? w0 : (z == 1) ? w1 : (z == 2) ? w2 : w3;
  u16* dst = (z == 0) ? d0 : (z == 1) ? d1 : (z == 2) ? d2 : d3;
  const int isf32 = *flag;
  const int tx = threadIdx.x & 31;
  const int ty = (threadIdx.x >> 5) * 4;
  const int bx = blockIdx.x * 32;
  const int by = blockIdx.y * 32;
#pragma unroll
  for (int r = 0; r < 4; ++r) {
    const int idx = (by + ty + r) * 1024 + bx + tx;
    tile[ty + r][tx] = isf32 ? f2bf(((const float*)src)[idx]) : ((const u16*)src)[idx];
  }
  __syncthreads();
#pragma unroll
  for (int r = 0; r < 4; ++r)
    dst[(bx + ty + r) * 1024 + by + tx] = tile[tx][ty + r];
}

// ---------------- 128x128xBK bf16 MFMA GEMM, m97-style -----------------------
// MODE 0 (BK=64): X @ WtQKV^T -> Q[bh][j][64], K[bh][j][64], Vt[bh][64][16]
// MODE 1 (BK=32): T @ WtO^T + bo -> out (fp32 or bf16 per flag)
template <int MODE, int BK>
__global__ __launch_bounds__(256) void gemm_kernel(
    const u16* __restrict__ X, const u16* __restrict__ Wt,
    const void* __restrict__ b0, const void* __restrict__ b1,
    const void* __restrict__ b2, void* __restrict__ o0, u16* __restrict__ o1,
    u16* __restrict__ o2, const int* __restrict__ flag) {
  constexpr int CPR = BK / 8;     // 16B chunks per row
  constexpr int NISS = BK / 16;   // async16 issues per matrix
  constexpr int KH = BK / 32;     // K=32 halves per iteration
  __shared__ alignas(16) u16 As[128 * BK];
  __shared__ alignas(16) u16 Bs[128 * BK];
  const int tid = threadIdx.x;
  const int wave = tid >> 6, lane = tid & 63;
  const int m0 = blockIdx.y * 128, n0 = blockIdx.x * 128;
  const int wm = (wave >> 1) * 64, wn = (wave & 1) * 64;
  const int fr = lane & 15, fq = lane >> 4;
  const int isf32 = *flag;

  f32x4 acc[4][4] = {};

  const u16* gA[NISS];
  const u16* gB[NISS];
  u16* lA[NISS];
  u16* lB[NISS];
#pragma unroll
  for (int i = 0; i < NISS; ++i) {
    const int slot = i * 256 + tid;
    const int row = slot / CPR, ch = (slot % CPR) * 8;
    gA[i] = X + (m0 + row) * 1024 + ch;
    gB[i] = Wt + (n0 + row) * 1024 + ch;
    lA[i] = As + (i * 256 + wave * 64) * 8;
    lB[i] = Bs + (i * 256 + wave * 64) * 8;
  }
  const u16* aRd = As + (wm + fr) * BK + fq * 8;
  const u16* bRd = Bs + (wn + fr) * BK + fq * 8;

  for (int kb = 0; kb < 1024 / BK; ++kb) {
    const int ko = kb * BK;
    if (kb) __syncthreads();
#pragma unroll
    for (int i = 0; i < NISS; ++i) async16(gA[i] + ko, lA[i]);
#pragma unroll
    for (int i = 0; i < NISS; ++i) async16(gB[i] + ko, lB[i]);
    __syncthreads();  // compiler emits s_waitcnt vmcnt(0) before s_barrier
    bf16x8 af[4][KH], bfr[4][KH];
#pragma unroll
    for (int h = 0; h < KH; ++h)
#pragma unroll
      for (int t = 0; t < 4; ++t) {
        af[t][h] = ld_frag(aRd + t * 16 * BK + h * 32);
        bfr[t][h] = ld_frag(bRd + t * 16 * BK + h * 32);
      }
#pragma unroll
    for (int h = 0; h < KH; ++h)
#pragma unroll
      for (int i = 0; i < 4; ++i)
#pragma unroll
        for (int j = 0; j < 4; ++j) acc[i][j] = MFMA16(af[i][h], bfr[j][h], acc[i][j]);
  }

  const int c = fr, g = fq;
  if (MODE == 0) {
    const int q = n0 >> 10;  // 0=Q,1=K,2=V
    const int nb = (n0 & 1023) + wn;
    const void* bp = (q == 0) ? b0 : ((q == 1) ? b1 : b2);
    u16* q0 = (u16*)o0;
#pragma unroll
    for (int tm = 0; tm < 4; ++tm) {
      const int mbase = m0 + wm + tm * 16;
      const int bidx = mbase >> 4;
#pragma unroll
      for (int tn = 0; tn < 4; ++tn) {
        const int nl = nb + tn * 16 + c;
        const int h = nl >> 6, d = nl & 63;
        const float bias = ld_bias(bp, nl, isf32);
        const int bh = bidx * 16 + h;
        if (q == 2) {
          u16x4 pk;
#pragma unroll
          for (int r = 0; r < 4; ++r) pk[r] = f2bf(acc[tm][tn][r] + bias);
          *reinterpret_cast<u16x4*>(&o2[(bh * 64 + d) * 16 + g * 4]) = pk;
        } else {
          u16* dstq = (q == 0) ? q0 : o1;
#pragma unroll
          for (int r = 0; r < 4; ++r) {
            const int j = g * 4 + r;
            dstq[(bh * 16 + j) * 64 + d] = f2bf(acc[tm][tn][r] + bias);
          }
        }
      }
    }
  } else {
#pragma unroll
    for (int tm = 0; tm < 4; ++tm) {
      const int m = m0 + wm + tm * 16 + g * 4;
#pragma unroll
      for (int tn = 0; tn < 4; ++tn) {
        const int n = n0 + wn + tn * 16 + c;
        const float bias = ld_bias(b0, n, isf32);
        if (isf32) {
#pragma unroll
          for (int r = 0; r < 4; ++r)
            ((float*)o0)[(m + r) * 1024 + n] = acc[tm][tn][r] + bias;
        } else {
#pragma unroll
          for (int r = 0; r < 4; ++r)
            ((u16*)o0)[(m + r) * 1024 + n] = f2bf(acc[tm][tn][r] + bias);
        }
      }
    }
  }
}

// ---------------- attention: one wave per (b,h), transposed chain ------------
// All operand transforms are register shuffles (c2frag), no LDS round-trips.
__global__ __launch_bounds__(256) void attn_kernel(
    const u16* __restrict__ Qb, const u16* __restrict__ Kb, const u16* __restrict__ Vt,
    const void* __restrict__ P, u16* __restrict__ Tb,
    const int* __restrict__ flag) {
  __shared__ alignas(16) u16 Pl[4096];   // P[p][i][j]
  __shared__ alignas(16) u16 Ptl[4096];  // P^T
  const int tid = threadIdx.x;
  const int isf32 = *flag;
#pragma unroll
  for (int i = 0; i < 16; ++i) {
    const int idx = i * 256 + tid;
    const u16 v = isf32 ? f2bf(((const float*)P)[idx]) : ((const u16*)P)[idx];
    Pl[idx] = v;
    const int p = idx >> 8, rc = idx & 255, rr = rc >> 4, cc = rc & 15;
    Ptl[(p << 8) + (cc << 4) + rr] = v;
  }
  __syncthreads();

  const int wave = tid >> 6, lane = tid & 63;
  const int bh = blockIdx.x * 4 + wave;
  const int fr = lane & 15, fq = lane >> 4;

  const u16* qb = Qb + bh * 1024;
  const u16* kb = Kb + bh * 1024;
  const u16* vb = Vt + bh * 1024;

  const bf16x8 qf0 = ld_frag(qb + fr * 64 + fq * 8);
  const bf16x8 qf1 = ld_frag(qb + fr * 64 + 32 + fq * 8);
  const bf16x8 kf0 = ld_frag(kb + fr * 64 + fq * 8);
  const bf16x8 kf1 = ld_frag(kb + fr * 64 + 32 + fq * 8);
  f32x4 S = {0.f, 0.f, 0.f, 0.f};
  S = MFMA16(qf0, kf0, S);
  S = MFMA16(qf1, kf1, S);
#pragma unroll
  for (int r = 0; r < 4; ++r) S[r] *= 0.125f;  // 1/sqrt(64)
  const bf16x8 St = c2frag(S, lane);  // S^T as A-operand, reused all irreps

  f32x4 Mt = {0.f, 0.f, 0.f, 0.f};
#pragma unroll 4
  for (int p = 0; p < 16; ++p) {
    const bf16x8 pl = ld_frag_lo(Pl + (p << 8) + fr * 16 + fq * 8, lane);
    const bf16x8 pt = ld_frag_lo(Ptl + (p << 8) + fr * 16 + fq * 8, lane);
    f32x4 z = {0.f, 0.f, 0.f, 0.f};
    const f32x4 ApT = MFMA16(St, pl, z);                 // (P_p S)^T
    const f32x4 BpT = MFMA16(pl, c2frag(ApT, lane), z);  // scores^T
    float e[4], s = 0.f;
#pragma unroll
    for (int r = 0; r < 4; ++r) {
      e[r] = __expf(BpT[r]);
      s += e[r];
    }
    s += __shfl_xor(s, 16);
    s += __shfl_xor(s, 32);
    const float rs = __frcp_rn(s);
    f32x4 w;
#pragma unroll
    for (int r = 0; r < 4; ++r) w[r] = e[r] * rs;
    Mt = MFMA16(pt, c2frag(w, lane), Mt);  // (w P_p)^T accumulated
  }

  const bf16x8 mb = c2frag(Mt, lane);  // M^T as B-operand

  const int b = bh >> 4, h = bh & 15;
  u16* outp = Tb + (b * 16 + fr) * 1024 + h * 64;  // fr = i (C-layout col)
#pragma unroll
  for (int dt = 0; dt < 4; ++dt) {
    const bf16x8 vf = ld_frag_lo(vb + (dt * 16 + fr) * 16 + fq * 8, lane);
    f32x4 z = {0.f, 0.f, 0.f, 0.f};
    const f32x4 ot = MFMA16(vf, mb, z);  // O^T tile: row=d, col=i
    u16x4 pk;
#pragma unroll
    for (int r = 0; r < 4; ++r) pk[r] = f2bf(ot[r]);
    *reinterpret_cast<u16x4*>(&outp[dt * 16 + fq * 4]) = pk;
  }
}

// ---------------- launcher ---------------------------------------------------
extern "C" void kernel_launch(void* const* d_in, const int* in_sizes, int n_in,
                              void* d_out, int out_size, void* d_ws, size_t ws_size,
                              hipStream_t stream) {
  const void* x = d_in[0];
  const void* proj = d_in[1];
  const void* Wq = d_in[2];
  const void* bq = d_in[3];
  const void* Wk = d_in[4];
  const void* bk = d_in[5];
  const void* Wv = d_in[6];
  const void* bv = d_in[7];
  const void* Wo = d_in[8];
  const void* bo = d_in[9];

  char* ws = (char*)d_ws;
  int* flag = (int*)ws;          ws += 256;
  u16* WtQKV = (u16*)ws;         ws += (size_t)3072 * 1024 * 2;
  u16* WtO   = (u16*)ws;         ws += (size_t)1024 * 1024 * 2;
  u16* Xb    = (u16*)ws;         ws += (size_t)16384 * 1024 * 2;
  u16* Qbuf  = (u16*)ws;         ws += (size_t)16384 * 1024 * 2;
  u16* Kbuf  = (u16*)ws;         ws += (size_t)16384 * 1024 * 2;
  u16* Vtb   = (u16*)ws;         ws += (size_t)16384 * 1024 * 2;
  u16* Tbuf  = (u16*)ws;         ws += (size_t)16384 * 1024 * 2;

  detect_dtype<<<1, 1024, 0, stream>>>((const u32*)x, flag);
  convert_x<<<16384, 256, 0, stream>>>(x, Xb, flag);
  transpose_conv<<<dim3(32, 32, 4), 256, 0, stream>>>(
      Wq, Wk, Wv, Wo, WtQKV, WtQKV + 1024 * 1024, WtQKV + 2 * 1024 * 1024, WtO, flag);

  gemm_kernel<0, 64><<<dim3(24, 128), 256, 0, stream>>>(
      Xb, WtQKV, bq, bk, bv, Qbuf, Kbuf, Vtb, flag);
  attn_kernel<<<4096, 256, 0, stream>>>(Qbuf, Kbuf, Vtb, proj, Tbuf, flag);
  gemm_kernel<1, 32><<<dim3(8, 128), 256, 0, stream>>>(
      Tbuf, WtO, bo, nullptr, nullptr, d_out, nullptr, nullptr, flag);
}